// Round 1
// baseline (527.804 us; speedup 1.0000x reference)
//
#include <hip/hip_runtime.h>

#define N_NODES 100000
#define N_EDGES 3200000
#define IN_FEAT 512
#define HID 16

// ---------------------------------------------------------------------------
// Edge-index dtype hedge: reference makes int64 edge_index; harness may hand
// us int32 or raw int64. Probe device-side: for int64 storage, every odd
// int32 word is a zero high-half (ids < 2^31). For int32 storage the odd
// words are random node ids (nonzero w.h.p.).
// ---------------------------------------------------------------------------
__global__ void k_detect(const void* ei, int* flag) {
    const int* p = (const int*)ei;
    int t = threadIdx.x;                     // 64 threads = 1 wave
    bool nz = (p[2 * t + 1] != 0);
    unsigned long long m = __ballot(nz);
    if (t == 0) *flag = (m == 0ull) ? 1 : 0; // 1 => int64 storage
}

__device__ __forceinline__ void load_edge(const void* ei, int is64, int e,
                                          int& s, int& d) {
    if (is64) {
        const long long* p = (const long long*)ei;
        s = (int)p[e];
        d = (int)p[(long long)N_EDGES + e];
    } else {
        const int* p = (const int*)ei;
        s = p[e];
        d = p[N_EDGES + e];
    }
}

__global__ void k_deg(const void* ei, const int* __restrict__ flag,
                      int* __restrict__ deg) {
    int is64 = *flag;
    int e = blockIdx.x * blockDim.x + threadIdx.x;
    if (e >= N_EDGES) return;
    int d;
    if (is64) d = (int)((const long long*)ei)[(long long)N_EDGES + e];
    else      d = ((const int*)ei)[N_EDGES + e];
    atomicAdd(&deg[d], 1);
}

__global__ void k_dinv(const int* __restrict__ deg, float* __restrict__ dinv) {
    int i = blockIdx.x * blockDim.x + threadIdx.x;
    if (i >= N_NODES) return;
    dinv[i] = rsqrtf((float)(deg[i] + 1));   // +1 self-loop; always > 0
}

// xw = x @ W1  (row per lane; W1 reads are wave-uniform -> scalar loads)
// also initializes out1 = b1 + xw * dinv^2   (self-loop term + bias)
__global__ void k_gemm1(const float* __restrict__ x, const float* __restrict__ W1,
                        const float* __restrict__ b1, const float* __restrict__ dinv,
                        float* __restrict__ xw, float* __restrict__ out1) {
    int row = blockIdx.x * blockDim.x + threadIdx.x;
    if (row >= N_NODES) return;
    const float4* xr = (const float4*)(x + (size_t)row * IN_FEAT);
    float acc[16];
#pragma unroll
    for (int f = 0; f < 16; ++f) acc[f] = 0.f;

#pragma unroll 1
    for (int k0 = 0; k0 < IN_FEAT; k0 += 16) {  // 16 floats = one 64B line
        float4 v0 = xr[k0 / 4 + 0];
        float4 v1 = xr[k0 / 4 + 1];
        float4 v2 = xr[k0 / 4 + 2];
        float4 v3 = xr[k0 / 4 + 3];
        float xv[16] = {v0.x, v0.y, v0.z, v0.w, v1.x, v1.y, v1.z, v1.w,
                        v2.x, v2.y, v2.z, v2.w, v3.x, v3.y, v3.z, v3.w};
#pragma unroll
        for (int kk = 0; kk < 16; ++kk) {
            const float* wr = W1 + (size_t)(k0 + kk) * HID;  // wave-uniform
#pragma unroll
            for (int f = 0; f < HID; ++f)
                acc[f] = fmaf(xv[kk], wr[f], acc[f]);
        }
    }

    float di = dinv[row];
    float nrm = di * di;
    float4* xwv = (float4*)(xw + (size_t)row * HID);
    float4* o1v = (float4*)(out1 + (size_t)row * HID);
#pragma unroll
    for (int q = 0; q < 4; ++q) {
        float4 a = make_float4(acc[4 * q], acc[4 * q + 1],
                               acc[4 * q + 2], acc[4 * q + 3]);
        xwv[q] = a;
        float4 o = make_float4(fmaf(a.x, nrm, b1[4 * q + 0]),
                               fmaf(a.y, nrm, b1[4 * q + 1]),
                               fmaf(a.z, nrm, b1[4 * q + 2]),
                               fmaf(a.w, nrm, b1[4 * q + 3]));
        o1v[q] = o;
    }
}

// layer-1 edge scatter: thread = (edge, feat); 16-lane groups share the
// 64B xw[src] line and the 64B out1[dst] line.
__global__ void k_scatter1(const void* ei, const int* __restrict__ flag,
                           const float* __restrict__ dinv,
                           const float* __restrict__ xw,
                           float* __restrict__ out1) {
    int is64 = *flag;
    int t = blockIdx.x * blockDim.x + threadIdx.x;   // < 51.2M, fits int
    int e = t >> 4;
    int f = t & 15;
    int s, d;
    load_edge(ei, is64, e, s, d);
    float nrm = dinv[s] * dinv[d];
    float v = xw[(size_t)s * HID + f] * nrm;
    atomicAdd(&out1[(size_t)d * HID + f], v);
}

// relu(out1) @ W2 ; h2 kept for the gather, out2 initialized with bias+self
__global__ void k_layer2(const float* __restrict__ out1, const float* __restrict__ W2,
                         const float* __restrict__ b2, const float* __restrict__ dinv,
                         float* __restrict__ h2, float* __restrict__ out2) {
    int i = blockIdx.x * blockDim.x + threadIdx.x;
    if (i >= N_NODES) return;
    const float4* hv = (const float4*)(out1 + (size_t)i * HID);
    float h[16];
#pragma unroll
    for (int q = 0; q < 4; ++q) {
        float4 v = hv[q];
        h[4 * q + 0] = fmaxf(v.x, 0.f);
        h[4 * q + 1] = fmaxf(v.y, 0.f);
        h[4 * q + 2] = fmaxf(v.z, 0.f);
        h[4 * q + 3] = fmaxf(v.w, 0.f);
    }
    float g0 = 0.f, g1 = 0.f;
#pragma unroll
    for (int f = 0; f < HID; ++f) {
        g0 = fmaf(h[f], W2[f * 2 + 0], g0);
        g1 = fmaf(h[f], W2[f * 2 + 1], g1);
    }
    float di = dinv[i];
    float nrm = di * di;
    float2* h2v = (float2*)(h2 + (size_t)i * 2);
    float2* o2v = (float2*)(out2 + (size_t)i * 2);
    *h2v = make_float2(g0, g1);
    *o2v = make_float2(fmaf(g0, nrm, b2[0]), fmaf(g1, nrm, b2[1]));
}

__global__ void k_scatter2(const void* ei, const int* __restrict__ flag,
                           const float* __restrict__ dinv,
                           const float* __restrict__ h2,
                           float* __restrict__ out2) {
    int is64 = *flag;
    int t = blockIdx.x * blockDim.x + threadIdx.x;   // < 6.4M
    int e = t >> 1;
    int c = t & 1;
    int s, d;
    load_edge(ei, is64, e, s, d);
    float nrm = dinv[s] * dinv[d];
    float v = h2[(size_t)s * 2 + c] * nrm;
    atomicAdd(&out2[(size_t)d * 2 + c], v);
}

__global__ void k_logsm(const float* __restrict__ out2, float* __restrict__ y) {
    int i = blockIdx.x * blockDim.x + threadIdx.x;
    if (i >= N_NODES) return;
    float2 v = ((const float2*)out2)[i];
    float m = fmaxf(v.x, v.y);
    float lse = m + logf(expf(v.x - m) + expf(v.y - m));
    ((float2*)y)[i] = make_float2(v.x - lse, v.y - lse);
}

extern "C" void kernel_launch(void* const* d_in, const int* in_sizes, int n_in,
                              void* d_out, int out_size, void* d_ws, size_t ws_size,
                              hipStream_t stream) {
    const float* x  = (const float*)d_in[0];
    const void*  ei = d_in[1];
    const float* W1 = (const float*)d_in[2];
    const float* b1 = (const float*)d_in[3];
    const float* W2 = (const float*)d_in[4];
    const float* b2 = (const float*)d_in[5];
    float* y = (float*)d_out;

    char* w = (char*)d_ws;
    int*   flag = (int*)(w + 0);
    int*   deg  = (int*)(w + 1024);
    float* dinv = (float*)(w + 401408);
    float* xw   = (float*)(w + 801792);
    float* out1 = (float*)(w + 7201792);
    float* h2   = (float*)(w + 13601792);
    float* out2 = (float*)(w + 14401792);
    // total ws use: ~15.3 MB

    hipMemsetAsync(deg, 0, (size_t)N_NODES * sizeof(int), stream);
    k_detect<<<1, 64, 0, stream>>>(ei, flag);
    k_deg<<<N_EDGES / 256, 256, 0, stream>>>(ei, flag, deg);
    k_dinv<<<(N_NODES + 255) / 256, 256, 0, stream>>>(deg, dinv);
    k_gemm1<<<(N_NODES + 255) / 256, 256, 0, stream>>>(x, W1, b1, dinv, xw, out1);
    k_scatter1<<<(N_EDGES * 16) / 256, 256, 0, stream>>>(ei, flag, dinv, xw, out1);
    k_layer2<<<(N_NODES + 255) / 256, 256, 0, stream>>>(out1, W2, b2, dinv, h2, out2);
    k_scatter2<<<(N_EDGES * 2) / 256, 256, 0, stream>>>(ei, flag, dinv, h2, out2);
    k_logsm<<<(N_NODES + 255) / 256, 256, 0, stream>>>(out2, y);
}